// Round 1
// baseline (228.445 us; speedup 1.0000x reference)
//
#include <hip/hip_runtime.h>

// Problem constants
#define BB 4
#define CC 16
#define HH 256
#define WW 256
#define NN (HH*WW)      // 65536
#define SS 100
#define NCH 64          // n-chunks per (b,q) for pass1 partials
#define NTCH (NN/NCH)   // 1024 n per chunk
#define SUB 64          // n per LDS subtile
#define SUBV 16         // SUB/4 (float4 groups)
#define EPSV 1e-32f

// ws layout (float offsets)
#define RELS_OFF  0u                      // [B][2][S][S]            = 80000
#define PPART_OFF 80000u                  // [B][2][NCH][C][S]       = 819200
#define QSUM_OFF  899200u                 // [B][2][NCH][S]          = 51200
#define SPFN_OFF  950400u                 // [B][2][C][S]            = 12800
#define PFSP_OFF  963200u                 // [B][C][N]               = 4194304
// total 5157504 floats = 20.6 MB

// K1: rels[b,q,s,t] = exp(-sum_c (spf[c,t]-spf[c,s])^2)   (OMEGA2 = 1)
__global__ __launch_bounds__(128) void k_rels(const float* __restrict__ spf1,
                                              const float* __restrict__ spf2,
                                              float* __restrict__ ws) {
    int s = blockIdx.x;   // 0..S-1
    int q = blockIdx.y;   // 0..1
    int b = blockIdx.z;   // 0..B-1
    const float* spf = (q ? spf2 : spf1) + (size_t)b * CC * SS;
    __shared__ float sp[CC][SS];
    for (int idx = threadIdx.x; idx < CC * SS; idx += 128)
        sp[idx / SS][idx % SS] = spf[idx];
    __syncthreads();
    int t = threadIdx.x;
    if (t < SS) {
        float d2 = 0.f;
        #pragma unroll
        for (int c = 0; c < CC; ++c) {
            float d = sp[c][t] - sp[c][s];
            d2 += d * d;
        }
        ws[RELS_OFF + ((size_t)(b * 2 + q) * SS + s) * SS + t] = expf(-d2);
    }
}

// K2: partial P[c,s] = sum_n pf[c,n]*Q[s,n] and qsum[s] = sum_n Q[s,n]
// One block per (b, q, 1024-n chunk). Thread owns (4 channels) x (2 s-slots).
__global__ __launch_bounds__(256) void k_pass1(const float* __restrict__ pf,
                                               const float* __restrict__ Q1,
                                               const float* __restrict__ Q2,
                                               float* __restrict__ ws) {
    int chunk = blockIdx.x;   // 0..NCH-1
    int q     = blockIdx.y;   // 0..1
    int b     = blockIdx.z;   // 0..B-1
    const float* Q  = (q ? Q2 : Q1) + (size_t)b * SS * NN;
    const float* PF = pf + (size_t)b * CC * NN;
    int n0 = chunk * NTCH;

    __shared__ float4 ldsQ[SUBV][129];   // [nn4][s-slot], lane-consecutive reads
    __shared__ float4 ldsP[CC][SUBV];    // broadcast reads

    int tid  = threadIdx.x;
    int wave = tid >> 6;
    int lane = tid & 63;
    int s0 = lane, s1 = lane + 64;
    int cbase = wave * 4;

    float acc[4][2] = {};
    float qa0 = 0.f, qa1 = 0.f;

    for (int sub = 0; sub < NTCH / SUB; ++sub) {
        int nb = n0 + sub * SUB;
        // stage pf subtile: 16 c x 16 float4 = 256 float4, one per thread
        {
            int c = tid >> 4, v = tid & 15;
            ldsP[c][v] = *(const float4*)(PF + (size_t)c * NN + nb + v * 4);
        }
        // stage Q subtile: 100 s x 16 float4
        for (int idx = tid; idx < SS * SUBV; idx += 256) {
            int s = idx >> 4, v = idx & 15;
            ldsQ[v][s] = *(const float4*)(Q + (size_t)s * NN + nb + v * 4);
        }
        __syncthreads();
        #pragma unroll 4
        for (int v = 0; v < SUBV; ++v) {
            float4 q0 = ldsQ[v][s0];
            float4 q1 = make_float4(0.f, 0.f, 0.f, 0.f);
            if (s1 < SS) q1 = ldsQ[v][s1];
            float4 p0 = ldsP[cbase + 0][v];
            float4 p1 = ldsP[cbase + 1][v];
            float4 p2 = ldsP[cbase + 2][v];
            float4 p3 = ldsP[cbase + 3][v];
            acc[0][0] += p0.x*q0.x; acc[0][0] += p0.y*q0.y; acc[0][0] += p0.z*q0.z; acc[0][0] += p0.w*q0.w;
            acc[1][0] += p1.x*q0.x; acc[1][0] += p1.y*q0.y; acc[1][0] += p1.z*q0.z; acc[1][0] += p1.w*q0.w;
            acc[2][0] += p2.x*q0.x; acc[2][0] += p2.y*q0.y; acc[2][0] += p2.z*q0.z; acc[2][0] += p2.w*q0.w;
            acc[3][0] += p3.x*q0.x; acc[3][0] += p3.y*q0.y; acc[3][0] += p3.z*q0.z; acc[3][0] += p3.w*q0.w;
            acc[0][1] += p0.x*q1.x; acc[0][1] += p0.y*q1.y; acc[0][1] += p0.z*q1.z; acc[0][1] += p0.w*q1.w;
            acc[1][1] += p1.x*q1.x; acc[1][1] += p1.y*q1.y; acc[1][1] += p1.z*q1.z; acc[1][1] += p1.w*q1.w;
            acc[2][1] += p2.x*q1.x; acc[2][1] += p2.y*q1.y; acc[2][1] += p2.z*q1.z; acc[2][1] += p2.w*q1.w;
            acc[3][1] += p3.x*q1.x; acc[3][1] += p3.y*q1.y; acc[3][1] += p3.z*q1.z; acc[3][1] += p3.w*q1.w;
            if (wave == 0) {
                qa0 += q0.x + q0.y + q0.z + q0.w;
                qa1 += q1.x + q1.y + q1.z + q1.w;
            }
        }
        __syncthreads();
    }

    size_t pbase = PPART_OFF + ((size_t)(b * 2 + q) * NCH + chunk) * CC * SS;
    #pragma unroll
    for (int i = 0; i < 4; ++i) {
        ws[pbase + (size_t)(cbase + i) * SS + s0] = acc[i][0];
        if (s1 < SS) ws[pbase + (size_t)(cbase + i) * SS + s1] = acc[i][1];
    }
    if (wave == 0) {
        size_t qb = QSUM_OFF + ((size_t)(b * 2 + q) * NCH + chunk) * SS;
        ws[qb + s0] = qa0;
        if (s1 < SS) ws[qb + s1] = qa1;
    }
}

// K3: reduce partials, then spf_n[c,s] = (sum_t rels[s,t] P[c,t]) / (sum_t rels[s,t] qsum[t] + eps)
__global__ __launch_bounds__(256) void k_finalize(float* __restrict__ ws) {
    int bq = blockIdx.x;  // 0..7
    __shared__ float P[CC * SS];
    __shared__ float qs[SS];
    __shared__ float den[SS];
    int tid = threadIdx.x;
    const float* pp = ws + PPART_OFF + (size_t)bq * NCH * CC * SS;
    for (int idx = tid; idx < CC * SS; idx += 256) {
        float a = 0.f;
        for (int ch = 0; ch < NCH; ++ch) a += pp[(size_t)ch * CC * SS + idx];
        P[idx] = a;
    }
    const float* qp = ws + QSUM_OFF + (size_t)bq * NCH * SS;
    if (tid < SS) {
        float a = 0.f;
        for (int ch = 0; ch < NCH; ++ch) a += qp[(size_t)ch * SS + tid];
        qs[tid] = a;
    }
    __syncthreads();
    const float* rl = ws + RELS_OFF + (size_t)bq * SS * SS;
    if (tid < SS) {
        float a = 0.f;
        for (int t = 0; t < SS; ++t) a += rl[(size_t)tid * SS + t] * qs[t];
        den[tid] = a + EPSV;
    }
    __syncthreads();
    float* sout = ws + SPFN_OFF + (size_t)bq * CC * SS;
    for (int idx = tid; idx < CC * SS; idx += 256) {
        int c = idx / SS, s = idx % SS;
        float a = 0.f;
        for (int t = 0; t < SS; ++t) a += rl[(size_t)s * SS + t] * P[c * SS + t];
        sout[idx] = a / den[s];
    }
}

// K4: pf_sp[c,n] = sum_s spf1n[c,s] Q1[s,n] + spf2n[c,s] Q2[s,n]
// Thread owns 2 consecutive pixels; spf_n staged transposed in LDS.
__global__ __launch_bounds__(256) void k_pass2(const float* __restrict__ Q1,
                                               const float* __restrict__ Q2,
                                               float* __restrict__ ws) {
    int blk = blockIdx.x;   // 0..N/512-1
    int b   = blockIdx.y;
    int n0  = blk * 512;
    __shared__ float sp[2][SS][CC];
    int tid = threadIdx.x;
    const float* spin = ws + SPFN_OFF + (size_t)b * 2 * CC * SS;
    for (int idx = tid; idx < 2 * CC * SS; idx += 256) {
        int qq  = idx / (CC * SS);
        int rem = idx % (CC * SS);
        int c = rem / SS, s = rem % SS;
        sp[qq][s][c] = spin[idx];
    }
    __syncthreads();
    int n = n0 + tid * 2;
    const float* q1p = Q1 + (size_t)b * SS * NN + n;
    const float* q2p = Q2 + (size_t)b * SS * NN + n;
    float acc[CC][2] = {};
    for (int s = 0; s < SS; ++s) {
        float2 v1 = *(const float2*)(q1p + (size_t)s * NN);
        float2 v2 = *(const float2*)(q2p + (size_t)s * NN);
        #pragma unroll
        for (int c4 = 0; c4 < 4; ++c4) {
            float4 s1v = *(const float4*)&sp[0][s][c4 * 4];
            float4 s2v = *(const float4*)&sp[1][s][c4 * 4];
            acc[c4*4+0][0] += s1v.x*v1.x + s2v.x*v2.x;
            acc[c4*4+1][0] += s1v.y*v1.x + s2v.y*v2.x;
            acc[c4*4+2][0] += s1v.z*v1.x + s2v.z*v2.x;
            acc[c4*4+3][0] += s1v.w*v1.x + s2v.w*v2.x;
            acc[c4*4+0][1] += s1v.x*v1.y + s2v.x*v2.y;
            acc[c4*4+1][1] += s1v.y*v1.y + s2v.y*v2.y;
            acc[c4*4+2][1] += s1v.z*v1.y + s2v.z*v2.y;
            acc[c4*4+3][1] += s1v.w*v1.y + s2v.w*v2.y;
        }
    }
    float* o = ws + PFSP_OFF + (size_t)b * CC * NN + n;
    #pragma unroll
    for (int c = 0; c < CC; ++c)
        *(float2*)(o + (size_t)c * NN) = make_float2(acc[c][0], acc[c][1]);
}

// K5: 3x3 conv (cross-correlation, SAME zero padding), 16 -> 2 channels, + bias
__global__ __launch_bounds__(256) void k_conv(const float* __restrict__ w_ds,
                                              const float* __restrict__ b_ds,
                                              const float* __restrict__ ws,
                                              float* __restrict__ out) {
    int b = blockIdx.y;
    int n = blockIdx.x * 256 + threadIdx.x;
    __shared__ float wl[2][CC][9];
    __shared__ float bl[2];
    for (int i = threadIdx.x; i < 2 * CC * 9; i += 256)
        ((float*)wl)[i] = w_ds[i];
    if (threadIdx.x < 2) bl[threadIdx.x] = b_ds[threadIdx.x];
    __syncthreads();
    int y = n >> 8, x = n & 255;
    const float* base = ws + PFSP_OFF + (size_t)b * CC * NN;
    float a0 = bl[0], a1 = bl[1];
    for (int c = 0; c < CC; ++c) {
        const float* pc = base + (size_t)c * NN;
        #pragma unroll
        for (int dy = -1; dy <= 1; ++dy) {
            int yy = y + dy;
            if (yy < 0 || yy >= HH) continue;
            #pragma unroll
            for (int dx = -1; dx <= 1; ++dx) {
                int xx = x + dx;
                if (xx < 0 || xx >= WW) continue;
                float v = pc[(size_t)yy * WW + xx];
                int k = (dy + 1) * 3 + (dx + 1);
                a0 += v * wl[0][c][k];
                a1 += v * wl[1][c][k];
            }
        }
    }
    out[((size_t)b * 2 + 0) * NN + n] = a0;
    out[((size_t)b * 2 + 1) * NN + n] = a1;
}

extern "C" void kernel_launch(void* const* d_in, const int* in_sizes, int n_in,
                              void* d_out, int out_size, void* d_ws, size_t ws_size,
                              hipStream_t stream) {
    const float* pf   = (const float*)d_in[0];
    const float* spf1 = (const float*)d_in[1];
    const float* spf2 = (const float*)d_in[2];
    const float* Q1   = (const float*)d_in[3];
    const float* Q2   = (const float*)d_in[4];
    const float* w_ds = (const float*)d_in[5];
    const float* b_ds = (const float*)d_in[6];
    float* ws  = (float*)d_ws;
    float* out = (float*)d_out;

    k_rels<<<dim3(SS, 2, BB), 128, 0, stream>>>(spf1, spf2, ws);
    k_pass1<<<dim3(NCH, 2, BB), 256, 0, stream>>>(pf, Q1, Q2, ws);
    k_finalize<<<8, 256, 0, stream>>>(ws);
    k_pass2<<<dim3(NN / 512, BB), 256, 0, stream>>>(Q1, Q2, ws);
    k_conv<<<dim3(NN / 256, BB), 256, 0, stream>>>(w_ds, b_ds, ws, out);
}

// Round 2
// 198.338 us; speedup vs baseline: 1.1518x; 1.1518x over previous
//
#include <hip/hip_runtime.h>

// Problem constants
#define BB 4
#define CC 16
#define HH 256
#define WW 256
#define NN (HH*WW)      // 65536
#define SS 100
#define NSLOT 16        // partial slots per (b,q): 8 chunks x 2 stripes
#define EPSV 1e-32f

// ws layout (float offsets)
#define RELS_OFF  0u                      // [B][2][S][S]            = 80000
#define PPART_OFF 80000u                  // [B*2][NSLOT][C][S]      = 204800
#define QSUM_OFF  284800u                 // [B*2][NSLOT][S]         = 12800
#define SPFN_OFF  297600u                 // [B*2][C][S]             = 12800
#define PFSP_OFF  310400u                 // [B][C][N]               = 4194304
// total 4504704 floats = 18.0 MB

__device__ __forceinline__ float dot4(const float4& a, const float4& b) {
    return a.x * b.x + a.y * b.y + a.z * b.z + a.w * b.w;
}
__device__ __forceinline__ void fma4(float4& a, float s, const float4& v) {
    a.x += s * v.x; a.y += s * v.y; a.z += s * v.z; a.w += s * v.w;
}

// K1: rels[b,q,s,t] = exp(-sum_c (spf[c,t]-spf[c,s])^2)   (OMEGA2 = 1)
__global__ __launch_bounds__(128) void k_rels(const float* __restrict__ spf1,
                                              const float* __restrict__ spf2,
                                              float* __restrict__ ws) {
    int s = blockIdx.x;   // 0..S-1
    int q = blockIdx.y;   // 0..1
    int b = blockIdx.z;   // 0..B-1
    const float* spf = (q ? spf2 : spf1) + (size_t)b * CC * SS;
    __shared__ float sp[CC][SS];
    for (int idx = threadIdx.x; idx < CC * SS; idx += 128)
        sp[idx / SS][idx % SS] = spf[idx];
    __syncthreads();
    int t = threadIdx.x;
    if (t < SS) {
        float d2 = 0.f;
        #pragma unroll
        for (int c = 0; c < CC; ++c) {
            float d = sp[c][t] - sp[c][s];
            d2 += d * d;
        }
        ws[RELS_OFF + ((size_t)(b * 2 + q) * SS + s) * SS + t] = expf(-d2);
    }
}

// K2: partial P[c,s] = sum_n pf[c,n]*Q[s,n], qsum[s] = sum_n Q[s,n]
// Pure register GEMM: no LDS, no barriers. Lanes own k-slices (float4 each),
// wave tile = 8c x 5s, block = 4 waves = {c-half} x {n-stripe}.
// Grid: x = s-tile (20), y = chunk (8), z = bq (8).
__global__ __launch_bounds__(256) void k_pass1(const float* __restrict__ pf,
                                               const float* __restrict__ Q1,
                                               const float* __restrict__ Q2,
                                               float* __restrict__ ws) {
    int stile = blockIdx.x;   // 0..19
    int chunk = blockIdx.y;   // 0..7
    int bq    = blockIdx.z;   // 0..7
    int b = bq >> 1, q = bq & 1;
    const float* Q  = (q ? Q2 : Q1) + (size_t)b * SS * NN;
    const float* PF = pf + (size_t)b * CC * NN;

    int tid = threadIdx.x, w = tid >> 6, lane = tid & 63;
    int chalf = w & 1, stripe = w >> 1;
    int cbase = chalf * 8, sbase = stile * 5;
    int nbase = chunk * 8192 + stripe * 4096 + lane * 4;

    // wave-uniform row bases (SGPRs); per-lane part stays a 32-bit voffset
    const float* prow[8];
    const float* qrow[5];
    #pragma unroll
    for (int ci = 0; ci < 8; ++ci) prow[ci] = PF + (size_t)(cbase + ci) * NN;
    #pragma unroll
    for (int si = 0; si < 5; ++si) qrow[si] = Q + (size_t)(sbase + si) * NN;

    float acc[8][5] = {};
    float qs[5] = {};

    #pragma unroll 2
    for (int k = 0; k < 16; ++k) {
        int voff = nbase + k * 256;
        float4 q4[5], p4[8];
        #pragma unroll
        for (int si = 0; si < 5; ++si) q4[si] = *(const float4*)(qrow[si] + voff);
        #pragma unroll
        for (int ci = 0; ci < 8; ++ci) p4[ci] = *(const float4*)(prow[ci] + voff);
        #pragma unroll
        for (int ci = 0; ci < 8; ++ci)
            #pragma unroll
            for (int si = 0; si < 5; ++si)
                acc[ci][si] += dot4(p4[ci], q4[si]);
        if (chalf == 0) {
            #pragma unroll
            for (int si = 0; si < 5; ++si)
                qs[si] += q4[si].x + q4[si].y + q4[si].z + q4[si].w;
        }
    }

    // 64-lane butterfly reduction
    #pragma unroll
    for (int m = 1; m < 64; m <<= 1) {
        #pragma unroll
        for (int ci = 0; ci < 8; ++ci)
            #pragma unroll
            for (int si = 0; si < 5; ++si)
                acc[ci][si] += __shfl_xor(acc[ci][si], m);
        #pragma unroll
        for (int si = 0; si < 5; ++si)
            qs[si] += __shfl_xor(qs[si], m);
    }

    if (lane == 0) {
        int slot = chunk * 2 + stripe;
        size_t pbase = PPART_OFF + ((size_t)bq * NSLOT + slot) * CC * SS;
        #pragma unroll
        for (int ci = 0; ci < 8; ++ci)
            #pragma unroll
            for (int si = 0; si < 5; ++si)
                ws[pbase + (size_t)(cbase + ci) * SS + sbase + si] = acc[ci][si];
        if (chalf == 0) {
            size_t qb = QSUM_OFF + ((size_t)bq * NSLOT + slot) * SS;
            #pragma unroll
            for (int si = 0; si < 5; ++si)
                ws[qb + sbase + si] = qs[si];
        }
    }
}

// K3: reduce partials, then spf_n[c,s] = (sum_t rels[s,t] P[c,t]) / (sum_t rels[s,t] qsum[t] + eps)
__global__ __launch_bounds__(256) void k_finalize(float* __restrict__ ws) {
    int bq = blockIdx.x;  // 0..7
    __shared__ float P[CC * SS];
    __shared__ float qs[SS];
    __shared__ float den[SS];
    int tid = threadIdx.x;
    const float* pp = ws + PPART_OFF + (size_t)bq * NSLOT * CC * SS;
    for (int idx = tid; idx < CC * SS; idx += 256) {
        float a = 0.f;
        for (int ch = 0; ch < NSLOT; ++ch) a += pp[(size_t)ch * CC * SS + idx];
        P[idx] = a;
    }
    const float* qp = ws + QSUM_OFF + (size_t)bq * NSLOT * SS;
    if (tid < SS) {
        float a = 0.f;
        for (int ch = 0; ch < NSLOT; ++ch) a += qp[(size_t)ch * SS + tid];
        qs[tid] = a;
    }
    __syncthreads();
    const float* rl = ws + RELS_OFF + (size_t)bq * SS * SS;
    if (tid < SS) {
        float a = 0.f;
        for (int t = 0; t < SS; ++t) a += rl[(size_t)tid * SS + t] * qs[t];
        den[tid] = a + EPSV;
    }
    __syncthreads();
    float* sout = ws + SPFN_OFF + (size_t)bq * CC * SS;
    for (int idx = tid; idx < CC * SS; idx += 256) {
        int c = idx / SS, s = idx % SS;
        float a = 0.f;
        for (int t = 0; t < SS; ++t) a += rl[(size_t)s * SS + t] * P[c * SS + t];
        sout[idx] = a / den[s];
    }
}

// K4: pf_sp[c,n] = sum_s spf1n[c,s] Q1[s,n] + spf2n[c,s] Q2[s,n]
// Thread owns 4 consecutive pixels (float4); spf_n staged transposed in LDS.
__global__ __launch_bounds__(256) void k_pass2(const float* __restrict__ Q1,
                                               const float* __restrict__ Q2,
                                               float* __restrict__ ws) {
    int blk = blockIdx.x;   // 0..N/1024-1
    int b   = blockIdx.y;
    __shared__ float sp[2][SS][CC];
    int tid = threadIdx.x;
    const float* spin = ws + SPFN_OFF + (size_t)b * 2 * CC * SS;
    for (int idx = tid; idx < 2 * CC * SS; idx += 256) {
        int qq  = idx / (CC * SS);
        int rem = idx % (CC * SS);
        int c = rem / SS, s = rem % SS;
        sp[qq][s][c] = spin[idx];
    }
    __syncthreads();
    int n = blk * 1024 + tid * 4;
    const float* q1p = Q1 + (size_t)b * SS * NN + n;
    const float* q2p = Q2 + (size_t)b * SS * NN + n;
    float4 acc[CC];
    #pragma unroll
    for (int c = 0; c < CC; ++c) acc[c] = make_float4(0.f, 0.f, 0.f, 0.f);
    #pragma unroll 2
    for (int s = 0; s < SS; ++s) {
        float4 v1 = *(const float4*)(q1p + (size_t)s * NN);
        float4 v2 = *(const float4*)(q2p + (size_t)s * NN);
        #pragma unroll
        for (int g = 0; g < 4; ++g) {
            float4 s1v = *(const float4*)&sp[0][s][g * 4];
            float4 s2v = *(const float4*)&sp[1][s][g * 4];
            fma4(acc[g * 4 + 0], s1v.x, v1); fma4(acc[g * 4 + 0], s2v.x, v2);
            fma4(acc[g * 4 + 1], s1v.y, v1); fma4(acc[g * 4 + 1], s2v.y, v2);
            fma4(acc[g * 4 + 2], s1v.z, v1); fma4(acc[g * 4 + 2], s2v.z, v2);
            fma4(acc[g * 4 + 3], s1v.w, v1); fma4(acc[g * 4 + 3], s2v.w, v2);
        }
    }
    float* o = ws + PFSP_OFF + (size_t)b * CC * NN + n;
    #pragma unroll
    for (int c = 0; c < CC; ++c)
        *(float4*)(o + (size_t)c * NN) = acc[c];
}

// K5: 3x3 conv (cross-correlation, SAME zero padding), 16 -> 2 channels, + bias
__global__ __launch_bounds__(256) void k_conv(const float* __restrict__ w_ds,
                                              const float* __restrict__ b_ds,
                                              const float* __restrict__ ws,
                                              float* __restrict__ out) {
    int b = blockIdx.y;
    int n = blockIdx.x * 256 + threadIdx.x;
    __shared__ float wl[2][CC][9];
    __shared__ float bl[2];
    for (int i = threadIdx.x; i < 2 * CC * 9; i += 256)
        ((float*)wl)[i] = w_ds[i];
    if (threadIdx.x < 2) bl[threadIdx.x] = b_ds[threadIdx.x];
    __syncthreads();
    int y = n >> 8, x = n & 255;
    const float* base = ws + PFSP_OFF + (size_t)b * CC * NN;
    float a0 = bl[0], a1 = bl[1];
    for (int c = 0; c < CC; ++c) {
        const float* pc = base + (size_t)c * NN;
        #pragma unroll
        for (int dy = -1; dy <= 1; ++dy) {
            int yy = y + dy;
            if (yy < 0 || yy >= HH) continue;
            #pragma unroll
            for (int dx = -1; dx <= 1; ++dx) {
                int xx = x + dx;
                if (xx < 0 || xx >= WW) continue;
                float v = pc[(size_t)yy * WW + xx];
                int k = (dy + 1) * 3 + (dx + 1);
                a0 += v * wl[0][c][k];
                a1 += v * wl[1][c][k];
            }
        }
    }
    out[((size_t)b * 2 + 0) * NN + n] = a0;
    out[((size_t)b * 2 + 1) * NN + n] = a1;
}

extern "C" void kernel_launch(void* const* d_in, const int* in_sizes, int n_in,
                              void* d_out, int out_size, void* d_ws, size_t ws_size,
                              hipStream_t stream) {
    const float* pf   = (const float*)d_in[0];
    const float* spf1 = (const float*)d_in[1];
    const float* spf2 = (const float*)d_in[2];
    const float* Q1   = (const float*)d_in[3];
    const float* Q2   = (const float*)d_in[4];
    const float* w_ds = (const float*)d_in[5];
    const float* b_ds = (const float*)d_in[6];
    float* ws  = (float*)d_ws;
    float* out = (float*)d_out;

    k_rels<<<dim3(SS, 2, BB), 128, 0, stream>>>(spf1, spf2, ws);
    k_pass1<<<dim3(20, 8, 8), 256, 0, stream>>>(pf, Q1, Q2, ws);
    k_finalize<<<8, 256, 0, stream>>>(ws);
    k_pass2<<<dim3(NN / 1024, BB), 256, 0, stream>>>(Q1, Q2, ws);
    k_conv<<<dim3(NN / 256, BB), 256, 0, stream>>>(w_ds, b_ds, ws, out);
}